// Round 13
// baseline (404.855 us; speedup 1.0000x reference)
//
#include <hip/hip_runtime.h>
#include <cstdint>
#include <cstddef>

// ---------------- common types / helpers ----------------
typedef __attribute__((ext_vector_type(8))) short bf16x8;
typedef __attribute__((ext_vector_type(4))) float f32x4;
typedef __attribute__((ext_vector_type(16))) float f32x16;

#define S_LEN 2048
#define SCALE2 0.10411754f   // 192^-0.5 * log2(e)

__device__ __forceinline__ ushort f2bf(float f) {
  uint32_t u = __float_as_uint(f);
  u = (u + 0x7FFFu + ((u >> 16) & 1u)) >> 16;
  return (ushort)u;
}
__device__ __forceinline__ float bf2f(ushort u) {
  return __uint_as_float(((uint32_t)u) << 16);
}

typedef __attribute__((address_space(1))) void GV;
typedef __attribute__((address_space(3))) void LV;
__device__ __forceinline__ void gload16(const void* g, void* l) {
  __builtin_amdgcn_global_load_lds((GV*)g, (LV*)l, 16, 0, 0);
}

__device__ __forceinline__ void store_out(float* p, float v) { *p = v; }
__device__ __forceinline__ void store_out(ushort* p, float v) { *p = f2bf(v); }

// ---------------- fp32 -> bf16 convert ----------------
__global__ void k_f32_to_bf16(const float* __restrict__ in, ushort* __restrict__ out, int n4) {
  int i = blockIdx.x * blockDim.x + threadIdx.x;
  int stride = gridDim.x * blockDim.x;
  for (; i < n4; i += stride) {
    float4 v = reinterpret_cast<const float4*>(in)[i];
    ushort4 o;
    o.x = f2bf(v.x); o.y = f2bf(v.y); o.z = f2bf(v.z); o.w = f2bf(v.w);
    reinterpret_cast<ushort4*>(out)[i] = o;
  }
}

// ---------------- fp32 (R,C) -> bf16 transposed (C,R) ----------------
__global__ void k_transpose_f32_bf16(const float* __restrict__ in, ushort* __restrict__ out,
                                     int R, int C) {
  __shared__ float tile[32][33];
  int c0 = blockIdx.x * 32, r0 = blockIdx.y * 32;
  int tx = threadIdx.x, ty = threadIdx.y;
#pragma unroll
  for (int i = 0; i < 32; i += 8) {
    int r = r0 + ty + i, c = c0 + tx;
    if (r < R && c < C) tile[ty + i][tx] = in[(size_t)r * C + c];
  }
  __syncthreads();
#pragma unroll
  for (int i = 0; i < 32; i += 8) {
    int c = c0 + ty + i, r = r0 + tx;
    if (r < R && c < C) out[(size_t)c * R + r] = f2bf(tile[tx][ty + i]);
  }
}

// ---------------- 128x128 bf16 GEMM (R1-R8 proven form) ----------------
template <typename OUT>
__global__ __launch_bounds__(256) void k_gemm(const ushort* __restrict__ A,
                                              const ushort* __restrict__ Bt,
                                              OUT* __restrict__ C, int K, int Nreal) {
  __shared__ ushort As[128 * 32];
  __shared__ ushort Bs[128 * 32];
  const int t = threadIdx.x, lane = t & 63, w = t >> 6;
  const int nwg = gridDim.x * gridDim.y;
  const int wg = blockIdx.y * gridDim.x + blockIdx.x;
  const int swz = (wg & 7) * (nwg >> 3) + (wg >> 3);
  const int m0 = (swz / gridDim.x) * 128, n0 = (swz % gridDim.x) * 128;
  const int wm = (w >> 1) * 64, wn = (w & 1) * 64;
  const int g = lane >> 4, q = lane & 15;
  f32x4 acc[4][4] = {};
  for (int kt = 0; kt < K; kt += 32) {
#pragma unroll
    for (int i = 0; i < 2; i++) {
      int idx = i * 256 + t;
      gload16(A + (size_t)(m0 + (idx >> 2)) * K + kt + (idx & 3) * 8,
              (char*)As + (size_t)(i * 256 + (w << 6)) * 16);
      gload16(Bt + (size_t)(n0 + (idx >> 2)) * K + kt + (idx & 3) * 8,
              (char*)Bs + (size_t)(i * 256 + (w << 6)) * 16);
    }
    __syncthreads();
    bf16x8 af[4], bfr[4];
#pragma unroll
    for (int mi = 0; mi < 4; mi++) af[mi] = *(const bf16x8*)(As + (wm + 16 * mi + q) * 32 + 8 * g);
#pragma unroll
    for (int ni = 0; ni < 4; ni++) bfr[ni] = *(const bf16x8*)(Bs + (wn + 16 * ni + q) * 32 + 8 * g);
#pragma unroll
    for (int mi = 0; mi < 4; mi++)
#pragma unroll
      for (int ni = 0; ni < 4; ni++)
        acc[mi][ni] = __builtin_amdgcn_mfma_f32_16x16x32_bf16(af[mi], bfr[ni], acc[mi][ni], 0, 0, 0);
    __syncthreads();
  }
#pragma unroll
  for (int mi = 0; mi < 4; mi++)
#pragma unroll
    for (int ni = 0; ni < 4; ni++) {
      int col = n0 + wn + 16 * ni + q;
      if (col < Nreal) {
        int row = m0 + wm + 16 * mi + 4 * g;
#pragma unroll
        for (int r = 0; r < 4; r++)
          store_out(&C[(size_t)(row + r) * Nreal + col], acc[mi][ni][r]);
      }
    }
}

// ---------------- kv GEMM (R1-R8 proven form): k_nope -> kbuf, V -> vT ----------------
__global__ __launch_bounds__(256) void k_gemm_kv(const ushort* __restrict__ A,
                                                 const ushort* __restrict__ Bt,
                                                 ushort* __restrict__ kbuf,
                                                 ushort* __restrict__ vT, int K) {
  __shared__ ushort As[128 * 32];
  __shared__ ushort Bs[128 * 32];
  const int t = threadIdx.x, lane = t & 63, w = t >> 6;
  const int nwg = gridDim.x * gridDim.y;
  const int wg = blockIdx.y * gridDim.x + blockIdx.x;
  const int swz = (wg & 7) * (nwg >> 3) + (wg >> 3);
  const int m0 = (swz / gridDim.x) * 128, n0 = (swz % gridDim.x) * 128;
  const int wm = (w >> 1) * 64, wn = (w & 1) * 64;
  const int g = lane >> 4, q = lane & 15;
  f32x4 acc[4][4] = {};
  for (int kt = 0; kt < K; kt += 32) {
#pragma unroll
    for (int i = 0; i < 2; i++) {
      int idx = i * 256 + t;
      gload16(A + (size_t)(m0 + (idx >> 2)) * K + kt + (idx & 3) * 8,
              (char*)As + (size_t)(i * 256 + (w << 6)) * 16);
      gload16(Bt + (size_t)(n0 + (idx >> 2)) * K + kt + (idx & 3) * 8,
              (char*)Bs + (size_t)(i * 256 + (w << 6)) * 16);
    }
    __syncthreads();
    bf16x8 af[4], bfr[4];
#pragma unroll
    for (int mi = 0; mi < 4; mi++) af[mi] = *(const bf16x8*)(As + (wm + 16 * mi + q) * 32 + 8 * g);
#pragma unroll
    for (int ni = 0; ni < 4; ni++) bfr[ni] = *(const bf16x8*)(Bs + (wn + 16 * ni + q) * 32 + 8 * g);
#pragma unroll
    for (int mi = 0; mi < 4; mi++)
#pragma unroll
      for (int ni = 0; ni < 4; ni++)
        acc[mi][ni] = __builtin_amdgcn_mfma_f32_16x16x32_bf16(af[mi], bfr[ni], acc[mi][ni], 0, 0, 0);
    __syncthreads();
  }
#pragma unroll
  for (int mi = 0; mi < 4; mi++)
#pragma unroll
    for (int ni = 0; ni < 4; ni++) {
      int col = n0 + wn + 16 * ni + q;     // 0..4095
      int hh = col >> 8, jj = col & 255;
      int row0 = m0 + wm + 16 * mi + 4 * g;
#pragma unroll
      for (int r = 0; r < 4; r++) {
        int tok = row0 + r;
        int bb = tok >> 11, ss = tok & 2047;
        ushort v = f2bf(acc[mi][ni][r]);
        if (jj < 128)
          kbuf[((size_t)(bb * 16 + hh) * 2048 + ss) * 192 + jj] = v;
        else
          vT[((size_t)(bb * 16 + hh) * 128 + (jj - 128)) * 2048 + ss] = v;
      }
    }
}

// ---------------- RMSNorm (fp32 in strided rows, bf16 out) ----------------
__global__ void k_rmsnorm_bf16(const float* __restrict__ in, const float* __restrict__ w,
                               ushort* __restrict__ out, int D, int instride) {
  int row = blockIdx.x;
  const float* x = in + (size_t)row * instride;
  ushort* o = out + (size_t)row * D;
  float ss = 0.f;
  for (int i = threadIdx.x; i < D; i += 256) { float v = x[i]; ss += v * v; }
#pragma unroll
  for (int m = 1; m < 64; m <<= 1) ss += __shfl_xor(ss, m);
  __shared__ float red[4];
  if ((threadIdx.x & 63) == 0) red[threadIdx.x >> 6] = ss;
  __syncthreads();
  float tot = red[0] + red[1] + red[2] + red[3];
  float sc = rsqrtf(tot / (float)D + 1e-6f);
  for (int i = threadIdx.x; i < D; i += 256) o[i] = f2bf(x[i] * sc * w[i]);
}

// ---------------- kv RMSNorm (512) + k_pe rope broadcast into kbuf ----------------
__global__ void k_kvnorm_rope(const float* __restrict__ cqkv, const float* __restrict__ w,
                              const float* __restrict__ cosT, const float* __restrict__ sinT,
                              ushort* __restrict__ ckvn, ushort* __restrict__ kbuf) {
  int tok = blockIdx.x, b = tok >> 11, s = tok & 2047;
  const float* x = cqkv + (size_t)tok * 2112 + 1536;
  float ss = 0.f;
  for (int i = threadIdx.x; i < 512; i += 256) { float v = x[i]; ss += v * v; }
#pragma unroll
  for (int m = 1; m < 64; m <<= 1) ss += __shfl_xor(ss, m);
  __shared__ float red[4];
  if ((threadIdx.x & 63) == 0) red[threadIdx.x >> 6] = ss;
  __syncthreads();
  float tot = red[0] + red[1] + red[2] + red[3];
  float sc = rsqrtf(tot / 512.f + 1e-6f);
  for (int i = threadIdx.x; i < 512; i += 256) ckvn[(size_t)tok * 512 + i] = f2bf(x[i] * sc * w[i]);
  if (threadIdx.x < 32) {
    int i = threadIdx.x;
    float xr = x[512 + 2 * i], xi = x[512 + 2 * i + 1];
    float c = cosT[s * 32 + i], sn = sinT[s * 32 + i];
    uint32_t lo = f2bf(xr * c - xi * sn);
    uint32_t hi = f2bf(xr * sn + xi * c);
    uint32_t pk = lo | (hi << 16);
#pragma unroll
    for (int h = 0; h < 16; ++h)
      *(uint32_t*)(kbuf + ((size_t)(b * 16 + h) * 2048 + s) * 192 + 128 + 2 * i) = pk;
  }
}

// ---------------- q rope, in-place on bf16 q (4096, 16, 192) ----------------
__global__ void k_qrope(ushort* __restrict__ qb, const float* __restrict__ cosT,
                        const float* __restrict__ sinT) {
  int tok = blockIdx.x, s = tok & (S_LEN - 1);
  for (int pp = threadIdx.x; pp < 512; pp += 256) {
    int h = pp >> 5, i = pp & 31;
    ushort* base = qb + ((size_t)tok * 16 + h) * 192 + 128;
    float xr = bf2f(base[2 * i]), xi = bf2f(base[2 * i + 1]);
    float c = cosT[s * 32 + i], sn = sinT[s * 32 + i];
    base[2 * i] = f2bf(xr * c - xi * sn);
    base[2 * i + 1] = f2bf(xr * sn + xi * c);
  }
}

// ---------------- causal flash attention: swapped-QK^T, 32x32 MFMA ----------------
// R13 deltas vs R7/R12-proven k_attn7 (mechanism: latency-bound kernel, pipes <30%):
//  1. Anti-symmetric qt mapping: id<256 -> qt=15-(id>>5); else qt=(id-256)>>5.
//     Blocks id and id+256 co-resident on the same CU sum to 68 iters
//     (was 40..96 -> tail imbalance, Occupancy 12.6%).
//  2. QK accumulator split into 2 chains (even/odd slabs) -> 6-deep dependent
//     MFMA chains instead of 12-deep; +16 VALU adds.
//  3. Tree (depth-4) max and sum reductions instead of 15-deep serial chains.
// Everything else byte-identical.
__global__ __launch_bounds__(256, 2) void k_attn9(const ushort* __restrict__ qb,
                                                  const ushort* __restrict__ kb,
                                                  const ushort* __restrict__ vT,
                                                  ushort* __restrict__ aout) {
  const int id = blockIdx.x;
  const int qt = (id < 256) ? (15 - (id >> 5)) : ((id - 256) >> 5);
  const int bh = id & 31;
  const int h = bh & 15, b = bh >> 4;

  const int t = threadIdx.x, lane = t & 63, w = t >> 6;
  const int lq = lane & 31, hi = lane >> 5;
  const int kx = (lq >> 3) & 3;              // read-side chunk XOR

  __shared__ ushort Ks[2][6656];   // 32 rows x 25 chunks (1 pad chunk/row) + tail
  __shared__ ushort Vs[2][5120];   // 128 rows x 5 chunks (1 pad chunk/row)

  const ushort* kh = kb + (size_t)(b * 16 + h) * (2048 * 192);
  const ushort* vh = vT + (size_t)(b * 16 + h) * (128 * 2048);

  auto stage = [&](int k0, int bi) {
#pragma unroll
    for (int it = 0; it < 4; ++it) {
      int ii = it * 4 + w;
      if (ii < 13) {
        unsigned s = ii * 64 + lane;
        int r = s / 25, cs = s - r * 25;
        if (r > 31) { r = 31; cs = 24; }
        int cg = cs ^ ((r >> 3) & 3);
        if (cg > 23) cg = 0;
        gload16(kh + (size_t)(k0 + r) * 192 + cg * 8, (char*)&Ks[bi][0] + ii * 1024);
      }
    }
#pragma unroll
    for (int it = 0; it < 3; ++it) {
      int ii = it * 4 + w;
      if (ii < 10) {
        unsigned s = ii * 64 + lane;
        int r = s / 5, cs = s - r * 5;
        int cg = cs ^ ((r >> 3) & 3);
        if (cg > 3) cg = 0;
        gload16(vh + (size_t)r * 2048 + k0 + cg * 8, (char*)&Vs[bi][0] + ii * 1024);
      }
    }
  };

  const int q0 = qt * 128;
  const int q0w = q0 + 32 * w;
  const int qg = q0w + lq;
  const int nkt = qt * 4 + 4;

  bf16x8 qf[12];
  {
    const ushort* qp = qb + ((size_t)(b * 2048 + qg) * 16 + h) * 192 + 8 * hi;
#pragma unroll
    for (int s = 0; s < 12; ++s) qf[s] = *(const bf16x8*)(qp + 16 * s);
  }

  f32x16 oacc[4];
#pragma unroll
  for (int db = 0; db < 4; ++db)
#pragma unroll
    for (int r = 0; r < 16; ++r) oacc[db][r] = 0.f;
  float m = -1e30f, l = 0.f;

  stage(0, 0);
  asm volatile("s_waitcnt vmcnt(0)" ::: "memory");
  __syncthreads();
  int cur = 0;

  for (int kt = 0; kt < nkt; ++kt) {
    const int k0 = kt * 32;
    if (kt + 1 < nkt) stage((kt + 1) * 32, cur ^ 1);
    const ushort* KB = &Ks[cur][0];
    const ushort* VB = &Vs[cur][0];
    if (k0 <= q0w + 31) {
      // ---- QK^T: two independent 6-deep MFMA chains (latency halved) ----
      f32x16 sacc0, sacc1;
#pragma unroll
      for (int r = 0; r < 16; ++r) { sacc0[r] = 0.f; sacc1[r] = 0.f; }
      __builtin_amdgcn_s_setprio(1);
#pragma unroll
      for (int s = 0; s < 12; s += 2) {
        bf16x8 kf0 = *(const bf16x8*)(KB + lq * 200 + (((2 * s + hi) ^ kx) << 3));
        bf16x8 kf1 = *(const bf16x8*)(KB + lq * 200 + (((2 * (s + 1) + hi) ^ kx) << 3));
        sacc0 = __builtin_amdgcn_mfma_f32_32x32x16_bf16(kf0, qf[s], sacc0, 0, 0, 0);
        sacc1 = __builtin_amdgcn_mfma_f32_32x32x16_bf16(kf1, qf[s + 1], sacc1, 0, 0, 0);
      }
      __builtin_amdgcn_s_setprio(0);
      float sv[16];
#pragma unroll
      for (int r = 0; r < 16; ++r) sv[r] = sacc0[r] + sacc1[r];
      if (k0 + 31 > q0w) {
#pragma unroll
        for (int r = 0; r < 16; ++r)
          if (k0 + (r & 3) + 8 * (r >> 2) + 4 * hi > qg) sv[r] = -1e30f;
      }
      // ---- tree max (depth 4) ----
      float x8[8];
#pragma unroll
      for (int i = 0; i < 8; ++i) x8[i] = fmaxf(sv[2 * i], sv[2 * i + 1]);
      float x4[4];
#pragma unroll
      for (int i = 0; i < 4; ++i) x4[i] = fmaxf(x8[2 * i], x8[2 * i + 1]);
      float pmax = fmaxf(fmaxf(x4[0], x4[1]), fmaxf(x4[2], x4[3]));
      pmax = fmaxf(pmax, __shfl_xor(pmax, 32));
      float smax = pmax * SCALE2;
      if (!__all(smax - m <= 8.0f)) {
        float mnew = fmaxf(m, smax);
        float a = exp2f(m - mnew);
        l *= a;
#pragma unroll
        for (int db = 0; db < 4; ++db)
#pragma unroll
          for (int r = 0; r < 16; ++r) oacc[db][r] *= a;
        m = mnew;
      }
      float e[16];
#pragma unroll
      for (int r = 0; r < 16; ++r) e[r] = exp2f(sv[r] * SCALE2 - m);
      // ---- tree sum (depth 4) ----
      float s8[8];
#pragma unroll
      for (int i = 0; i < 8; ++i) s8[i] = e[2 * i] + e[2 * i + 1];
      float s4[4];
#pragma unroll
      for (int i = 0; i < 4; ++i) s4[i] = s8[2 * i] + s8[2 * i + 1];
      float sum = (s4[0] + s4[1]) + (s4[2] + s4[3]);
      sum += __shfl_xor(sum, 32);
      l += sum;
      uint32_t pk[8];
#pragma unroll
      for (int i = 0; i < 8; ++i)
        pk[i] = (uint32_t)f2bf(e[2 * i]) | ((uint32_t)f2bf(e[2 * i + 1]) << 16);
      uint32_t sw[8];
#pragma unroll
      for (int i = 0; i < 8; ++i) sw[i] = (uint32_t)__shfl_xor((int)pk[i], 32);
      union { uint32_t u[4]; bf16x8 v; } p0, p1;
      p0.u[0] = hi ? sw[2] : pk[0];
      p0.u[1] = hi ? sw[3] : pk[1];
      p0.u[2] = hi ? pk[2] : sw[0];
      p0.u[3] = hi ? pk[3] : sw[1];
      p1.u[0] = hi ? sw[6] : pk[4];
      p1.u[1] = hi ? sw[7] : pk[5];
      p1.u[2] = hi ? pk[6] : sw[4];
      p1.u[3] = hi ? pk[7] : sw[5];
      __builtin_amdgcn_s_setprio(1);
#pragma unroll
      for (int db = 0; db < 4; ++db) {
        bf16x8 vf0 = *(const bf16x8*)(VB + (32 * db + lq) * 40 + ((hi ^ kx) << 3));
        bf16x8 vf1 = *(const bf16x8*)(VB + (32 * db + lq) * 40 + (((2 + hi) ^ kx) << 3));
        oacc[db] = __builtin_amdgcn_mfma_f32_32x32x16_bf16(vf0, p0.v, oacc[db], 0, 0, 0);
        oacc[db] = __builtin_amdgcn_mfma_f32_32x32x16_bf16(vf1, p1.v, oacc[db], 0, 0, 0);
      }
      __builtin_amdgcn_s_setprio(0);
    }
    asm volatile("s_waitcnt vmcnt(0) lgkmcnt(0)" ::: "memory");
    __syncthreads();
    cur ^= 1;
  }

  float inv = 1.f / l;
  ushort* op = aout + ((size_t)(b * 2048 + qg)) * 2048 + h * 128 + 4 * hi;
#pragma unroll
  for (int db = 0; db < 4; ++db)
#pragma unroll
    for (int i = 0; i < 8; ++i) {
      uint32_t u = (uint32_t)f2bf(oacc[db][2 * i] * inv) |
                   ((uint32_t)f2bf(oacc[db][2 * i + 1] * inv) << 16);
      int dbase = 32 * db + (i & 1) * 2 + (i >> 1) * 8;
      *(uint32_t*)(op + dbase) = u;
    }
}

// ---------------- launcher ----------------
extern "C" void kernel_launch(void* const* d_in, const int* in_sizes, int n_in,
                              void* d_out, int out_size, void* d_ws, size_t ws_size,
                              hipStream_t stream) {
  const float* x = (const float*)d_in[0];
  const float* fcos = (const float*)d_in[1];
  const float* fsin = (const float*)d_in[2];
  const float* wq_a = (const float*)d_in[3];
  const float* qnw = (const float*)d_in[4];
  const float* wq_b = (const float*)d_in[5];
  const float* wkv_a = (const float*)d_in[6];
  const float* kvnw = (const float*)d_in[7];
  const float* wkv_b = (const float*)d_in[8];
  const float* wo = (const float*)d_in[9];
  float* out = (float*)d_out;

  char* ws = (char*)d_ws;
  size_t off = 0;
  auto alloc = [&](size_t bytes) -> char* {
    char* p = ws + off;
    off += (bytes + 255) & ~(size_t)255;
    return p;
  };
  ushort* xb     = (ushort*)alloc(4096ull * 2048 * 2);
  ushort* wqkv_t = (ushort*)alloc(2176ull * 2048 * 2);   // rows 0-1535 wq_a^T, 1536-2111 wkv_a^T, rest pad
  ushort* wqb_t  = (ushort*)alloc(3072ull * 1536 * 2);
  ushort* wkvb_t = (ushort*)alloc(4096ull * 512 * 2);
  ushort* wo_t   = (ushort*)alloc(2048ull * 2048 * 2);
  float*  cqkv   = (float*)alloc(4096ull * 2112 * 4);    // fused q_lora | kv_lora | k_pe
  ushort* cqn    = (ushort*)alloc(4096ull * 1536 * 2);
  ushort* ckvn   = (ushort*)alloc(4096ull * 512 * 2);
  ushort* kbuf   = (ushort*)alloc(2ull * 16 * 2048 * 192 * 2);
  ushort* qbuf   = (ushort*)cqkv;   // reuse: cqkv dead after both norms (34.6MB >= 25.2MB)
  ushort* aout   = xb;              // reuse: x dead after fused GEMM1
  ushort* vT     = wqkv_t;          // reuse: wqkv_t+wqb_t dead after GEMM2, vT needs 16.8MB

  dim3 tb(32, 8);
  k_f32_to_bf16<<<2048, 256, 0, stream>>>(x, xb, 4096 * 2048 / 4);
  k_transpose_f32_bf16<<<dim3(48, 64), tb, 0, stream>>>(wq_a, wqkv_t, 2048, 1536);
  k_transpose_f32_bf16<<<dim3(18, 64), tb, 0, stream>>>(wkv_a, wqkv_t + 1536ull * 2048, 2048, 576);
  k_transpose_f32_bf16<<<dim3(96, 48), tb, 0, stream>>>(wq_b, wqb_t, 1536, 3072);
  k_transpose_f32_bf16<<<dim3(128, 16), tb, 0, stream>>>(wkv_b, wkvb_t, 512, 4096);
  k_transpose_f32_bf16<<<dim3(64, 64), tb, 0, stream>>>(wo, wo_t, 2048, 2048);

  // fused GEMM1: cqkv = xb @ [wq_a | wkv_a]  (M=4096, K=2048, Nreal=2112; grid 17x32=544, %8==0)
  k_gemm<float><<<dim3(17, 32), 256, 0, stream>>>(xb, wqkv_t, cqkv, 2048, 2112);

  k_rmsnorm_bf16<<<4096, 256, 0, stream>>>(cqkv, qnw, cqn, 1536, 2112);
  k_kvnorm_rope<<<4096, 256, 0, stream>>>(cqkv, kvnw, fcos, fsin, ckvn, kbuf);

  // q = cqn @ wq_b (K=1536, N=3072), bf16 out (last reader of wqb_t and cqkv-as-input)
  k_gemm<ushort><<<dim3(24, 32), 256, 0, stream>>>(cqn, wqb_t, qbuf, 1536, 3072);
  k_qrope<<<4096, 256, 0, stream>>>(qbuf, fcos, fsin);

  // kv = ckvn @ wkv_b (K=512, N=4096) -> kbuf + vT (scatter epilogue)
  k_gemm_kv<<<dim3(32, 32), 256, 0, stream>>>(ckvn, wkvb_t, kbuf, vT, 512);

  k_attn9<<<dim3(512), 256, 0, stream>>>(qbuf, kbuf, vT, aout);

  // out = aout @ wo (K=2048, N=2048), fp32 out
  k_gemm<float><<<dim3(16, 32), 256, 0, stream>>>(aout, wo_t, out, 2048, 2048);
}

// Round 14
// 388.073 us; speedup vs baseline: 1.0432x; 1.0432x over previous
//
#include <hip/hip_runtime.h>
#include <cstdint>
#include <cstddef>

// ---------------- common types / helpers ----------------
typedef __attribute__((ext_vector_type(8))) short bf16x8;
typedef __attribute__((ext_vector_type(4))) float f32x4;
typedef __attribute__((ext_vector_type(16))) float f32x16;

#define S_LEN 2048
#define SCALE2 0.10411754f   // 192^-0.5 * log2(e)

__device__ __forceinline__ ushort f2bf(float f) {
  uint32_t u = __float_as_uint(f);
  u = (u + 0x7FFFu + ((u >> 16) & 1u)) >> 16;
  return (ushort)u;
}
__device__ __forceinline__ float bf2f(ushort u) {
  return __uint_as_float(((uint32_t)u) << 16);
}

typedef __attribute__((address_space(1))) void GV;
typedef __attribute__((address_space(3))) void LV;
__device__ __forceinline__ void gload16(const void* g, void* l) {
  __builtin_amdgcn_global_load_lds((GV*)g, (LV*)l, 16, 0, 0);
}

__device__ __forceinline__ void store_out(float* p, float v) { *p = v; }
__device__ __forceinline__ void store_out(ushort* p, float v) { *p = f2bf(v); }

// ---------------- fp32 -> bf16 convert ----------------
__global__ void k_f32_to_bf16(const float* __restrict__ in, ushort* __restrict__ out, int n4) {
  int i = blockIdx.x * blockDim.x + threadIdx.x;
  int stride = gridDim.x * blockDim.x;
  for (; i < n4; i += stride) {
    float4 v = reinterpret_cast<const float4*>(in)[i];
    ushort4 o;
    o.x = f2bf(v.x); o.y = f2bf(v.y); o.z = f2bf(v.z); o.w = f2bf(v.w);
    reinterpret_cast<ushort4*>(out)[i] = o;
  }
}

// ---------------- fp32 (R,C) -> bf16 transposed (C,R) ----------------
__global__ void k_transpose_f32_bf16(const float* __restrict__ in, ushort* __restrict__ out,
                                     int R, int C) {
  __shared__ float tile[32][33];
  int c0 = blockIdx.x * 32, r0 = blockIdx.y * 32;
  int tx = threadIdx.x, ty = threadIdx.y;
#pragma unroll
  for (int i = 0; i < 32; i += 8) {
    int r = r0 + ty + i, c = c0 + tx;
    if (r < R && c < C) tile[ty + i][tx] = in[(size_t)r * C + c];
  }
  __syncthreads();
#pragma unroll
  for (int i = 0; i < 32; i += 8) {
    int c = c0 + ty + i, r = r0 + tx;
    if (r < R && c < C) out[(size_t)c * R + r] = f2bf(tile[tx][ty + i]);
  }
}

// ---------------- 128x128 bf16 GEMM (R1-R8 proven form) ----------------
template <typename OUT>
__global__ __launch_bounds__(256) void k_gemm(const ushort* __restrict__ A,
                                              const ushort* __restrict__ Bt,
                                              OUT* __restrict__ C, int K, int Nreal) {
  __shared__ ushort As[128 * 32];
  __shared__ ushort Bs[128 * 32];
  const int t = threadIdx.x, lane = t & 63, w = t >> 6;
  const int nwg = gridDim.x * gridDim.y;
  const int wg = blockIdx.y * gridDim.x + blockIdx.x;
  const int swz = (wg & 7) * (nwg >> 3) + (wg >> 3);
  const int m0 = (swz / gridDim.x) * 128, n0 = (swz % gridDim.x) * 128;
  const int wm = (w >> 1) * 64, wn = (w & 1) * 64;
  const int g = lane >> 4, q = lane & 15;
  f32x4 acc[4][4] = {};
  for (int kt = 0; kt < K; kt += 32) {
#pragma unroll
    for (int i = 0; i < 2; i++) {
      int idx = i * 256 + t;
      gload16(A + (size_t)(m0 + (idx >> 2)) * K + kt + (idx & 3) * 8,
              (char*)As + (size_t)(i * 256 + (w << 6)) * 16);
      gload16(Bt + (size_t)(n0 + (idx >> 2)) * K + kt + (idx & 3) * 8,
              (char*)Bs + (size_t)(i * 256 + (w << 6)) * 16);
    }
    __syncthreads();
    bf16x8 af[4], bfr[4];
#pragma unroll
    for (int mi = 0; mi < 4; mi++) af[mi] = *(const bf16x8*)(As + (wm + 16 * mi + q) * 32 + 8 * g);
#pragma unroll
    for (int ni = 0; ni < 4; ni++) bfr[ni] = *(const bf16x8*)(Bs + (wn + 16 * ni + q) * 32 + 8 * g);
#pragma unroll
    for (int mi = 0; mi < 4; mi++)
#pragma unroll
      for (int ni = 0; ni < 4; ni++)
        acc[mi][ni] = __builtin_amdgcn_mfma_f32_16x16x32_bf16(af[mi], bfr[ni], acc[mi][ni], 0, 0, 0);
    __syncthreads();
  }
#pragma unroll
  for (int mi = 0; mi < 4; mi++)
#pragma unroll
    for (int ni = 0; ni < 4; ni++) {
      int col = n0 + wn + 16 * ni + q;
      if (col < Nreal) {
        int row = m0 + wm + 16 * mi + 4 * g;
#pragma unroll
        for (int r = 0; r < 4; r++)
          store_out(&C[(size_t)(row + r) * Nreal + col], acc[mi][ni][r]);
      }
    }
}

// ---------------- kv GEMM (R1-R8 proven form): k_nope -> kbuf, V -> vT ----------------
__global__ __launch_bounds__(256) void k_gemm_kv(const ushort* __restrict__ A,
                                                 const ushort* __restrict__ Bt,
                                                 ushort* __restrict__ kbuf,
                                                 ushort* __restrict__ vT, int K) {
  __shared__ ushort As[128 * 32];
  __shared__ ushort Bs[128 * 32];
  const int t = threadIdx.x, lane = t & 63, w = t >> 6;
  const int nwg = gridDim.x * gridDim.y;
  const int wg = blockIdx.y * gridDim.x + blockIdx.x;
  const int swz = (wg & 7) * (nwg >> 3) + (wg >> 3);
  const int m0 = (swz / gridDim.x) * 128, n0 = (swz % gridDim.x) * 128;
  const int wm = (w >> 1) * 64, wn = (w & 1) * 64;
  const int g = lane >> 4, q = lane & 15;
  f32x4 acc[4][4] = {};
  for (int kt = 0; kt < K; kt += 32) {
#pragma unroll
    for (int i = 0; i < 2; i++) {
      int idx = i * 256 + t;
      gload16(A + (size_t)(m0 + (idx >> 2)) * K + kt + (idx & 3) * 8,
              (char*)As + (size_t)(i * 256 + (w << 6)) * 16);
      gload16(Bt + (size_t)(n0 + (idx >> 2)) * K + kt + (idx & 3) * 8,
              (char*)Bs + (size_t)(i * 256 + (w << 6)) * 16);
    }
    __syncthreads();
    bf16x8 af[4], bfr[4];
#pragma unroll
    for (int mi = 0; mi < 4; mi++) af[mi] = *(const bf16x8*)(As + (wm + 16 * mi + q) * 32 + 8 * g);
#pragma unroll
    for (int ni = 0; ni < 4; ni++) bfr[ni] = *(const bf16x8*)(Bs + (wn + 16 * ni + q) * 32 + 8 * g);
#pragma unroll
    for (int mi = 0; mi < 4; mi++)
#pragma unroll
      for (int ni = 0; ni < 4; ni++)
        acc[mi][ni] = __builtin_amdgcn_mfma_f32_16x16x32_bf16(af[mi], bfr[ni], acc[mi][ni], 0, 0, 0);
    __syncthreads();
  }
#pragma unroll
  for (int mi = 0; mi < 4; mi++)
#pragma unroll
    for (int ni = 0; ni < 4; ni++) {
      int col = n0 + wn + 16 * ni + q;     // 0..4095
      int hh = col >> 8, jj = col & 255;
      int row0 = m0 + wm + 16 * mi + 4 * g;
#pragma unroll
      for (int r = 0; r < 4; r++) {
        int tok = row0 + r;
        int bb = tok >> 11, ss = tok & 2047;
        ushort v = f2bf(acc[mi][ni][r]);
        if (jj < 128)
          kbuf[((size_t)(bb * 16 + hh) * 2048 + ss) * 192 + jj] = v;
        else
          vT[((size_t)(bb * 16 + hh) * 128 + (jj - 128)) * 2048 + ss] = v;
      }
    }
}

// ---------------- RMSNorm (fp32 in strided rows, bf16 out) ----------------
__global__ void k_rmsnorm_bf16(const float* __restrict__ in, const float* __restrict__ w,
                               ushort* __restrict__ out, int D, int instride) {
  int row = blockIdx.x;
  const float* x = in + (size_t)row * instride;
  ushort* o = out + (size_t)row * D;
  float ss = 0.f;
  for (int i = threadIdx.x; i < D; i += 256) { float v = x[i]; ss += v * v; }
#pragma unroll
  for (int m = 1; m < 64; m <<= 1) ss += __shfl_xor(ss, m);
  __shared__ float red[4];
  if ((threadIdx.x & 63) == 0) red[threadIdx.x >> 6] = ss;
  __syncthreads();
  float tot = red[0] + red[1] + red[2] + red[3];
  float sc = rsqrtf(tot / (float)D + 1e-6f);
  for (int i = threadIdx.x; i < D; i += 256) o[i] = f2bf(x[i] * sc * w[i]);
}

// ---------------- kv RMSNorm (512) + k_pe rope broadcast into kbuf ----------------
__global__ void k_kvnorm_rope(const float* __restrict__ cqkv, const float* __restrict__ w,
                              const float* __restrict__ cosT, const float* __restrict__ sinT,
                              ushort* __restrict__ ckvn, ushort* __restrict__ kbuf) {
  int tok = blockIdx.x, b = tok >> 11, s = tok & 2047;
  const float* x = cqkv + (size_t)tok * 2112 + 1536;
  float ss = 0.f;
  for (int i = threadIdx.x; i < 512; i += 256) { float v = x[i]; ss += v * v; }
#pragma unroll
  for (int m = 1; m < 64; m <<= 1) ss += __shfl_xor(ss, m);
  __shared__ float red[4];
  if ((threadIdx.x & 63) == 0) red[threadIdx.x >> 6] = ss;
  __syncthreads();
  float tot = red[0] + red[1] + red[2] + red[3];
  float sc = rsqrtf(tot / 512.f + 1e-6f);
  for (int i = threadIdx.x; i < 512; i += 256) ckvn[(size_t)tok * 512 + i] = f2bf(x[i] * sc * w[i]);
  if (threadIdx.x < 32) {
    int i = threadIdx.x;
    float xr = x[512 + 2 * i], xi = x[512 + 2 * i + 1];
    float c = cosT[s * 32 + i], sn = sinT[s * 32 + i];
    uint32_t lo = f2bf(xr * c - xi * sn);
    uint32_t hi = f2bf(xr * sn + xi * c);
    uint32_t pk = lo | (hi << 16);
#pragma unroll
    for (int h = 0; h < 16; ++h)
      *(uint32_t*)(kbuf + ((size_t)(b * 16 + h) * 2048 + s) * 192 + 128 + 2 * i) = pk;
  }
}

// ---------------- q rope, in-place on bf16 q (4096, 16, 192) ----------------
__global__ void k_qrope(ushort* __restrict__ qb, const float* __restrict__ cosT,
                        const float* __restrict__ sinT) {
  int tok = blockIdx.x, s = tok & (S_LEN - 1);
  for (int pp = threadIdx.x; pp < 512; pp += 256) {
    int h = pp >> 5, i = pp & 31;
    ushort* base = qb + ((size_t)tok * 16 + h) * 192 + 128;
    float xr = bf2f(base[2 * i]), xi = bf2f(base[2 * i + 1]);
    float c = cosT[s * 32 + i], sn = sinT[s * 32 + i];
    base[2 * i] = f2bf(xr * c - xi * sn);
    base[2 * i + 1] = f2bf(xr * sn + xi * c);
  }
}

// ---------------- causal flash attention: swapped-QK^T, 32x32 MFMA, KVBLK=64 ----------------
// R14 delta vs R7 (proven 119.6us): KVBLK 32 -> 64. Halves iteration count ->
// halves per-k barrier/drain/softmax-pass overhead; 40 MFMA per barrier (was 20).
// Single-buffer LDS (43KB): Ks 64x200 (25600B exact, 1600 chunks), Vs 128x72
// (18432B, 1152 chunks). Serial stage -> vmcnt(0) -> barrier -> compute ->
// lgkm(0) -> barrier (R4/R8 proved pipelining is value-neutral here).
// K sub-blocks A (rows lq, k0+kk) and B (rows lq+32, k0+32+kk) share the same
// read XOR kx since ((lq+32)>>3)&3 == (lq>>3)&3. V rows 9 chunks (8 data+pad),
// read chunk (2*ks+hi)^vx, vx=((32*db+lq)>>3)&7 -- XOR of values <8 stays <8.
__global__ __launch_bounds__(256, 2) void k_attn10(const ushort* __restrict__ qb,
                                                   const ushort* __restrict__ kb,
                                                   const ushort* __restrict__ vT,
                                                   ushort* __restrict__ aout) {
  const int id = blockIdx.x;
  const int qt = 15 - (id >> 5);             // heavy-first (R7-proven mapping)
  const int bh = id & 31;
  const int h = bh & 15, b = bh >> 4;

  const int t = threadIdx.x, lane = t & 63, w = t >> 6;
  const int lq = lane & 31, hi = lane >> 5;
  const int kx = (lq >> 3) & 3;

  __shared__ ushort Ks[64 * 200];   // 25600 B
  __shared__ ushort Vs[128 * 72];   // 18432 B

  const ushort* kh = kb + (size_t)(b * 16 + h) * (2048 * 192);
  const ushort* vh = vT + (size_t)(b * 16 + h) * (128 * 2048);

  auto stage = [&](int k0) {
    // K: 1600 chunks (64 rows x 25), 25 wave-slots of 64
#pragma unroll
    for (int it = 0; it < 7; ++it) {
      int ii = it * 4 + w;
      if (ii < 25) {
        unsigned s = ii * 64 + lane;         // 0..1599
        int r = s / 25, e = s - r * 25;      // r<64, e<25 (e==24 pad)
        int cg = e ^ ((r >> 3) & 3);
        if (cg > 23) cg = 0;                 // pad slot -> dummy load
        gload16(kh + (size_t)(k0 + r) * 192 + cg * 8, (char*)Ks + ii * 1024);
      }
    }
    // V: 1152 chunks (128 rows x 9), 18 wave-slots
#pragma unroll
    for (int it = 0; it < 5; ++it) {
      int ii = it * 4 + w;
      if (ii < 18) {
        unsigned s = ii * 64 + lane;         // 0..1151
        int r = s / 9, e = s - r * 9;        // r<128, e<9 (e==8 pad)
        int cg = e ^ ((r >> 3) & 7);
        if (cg > 7) cg = 0;                  // pad slot -> dummy load
        gload16(vh + (size_t)r * 2048 + k0 + cg * 8, (char*)Vs + ii * 1024);
      }
    }
  };

  const int q0 = qt * 128;
  const int q0w = q0 + 32 * w;
  const int qg = q0w + lq;
  const int nkt = qt * 2 + 2;

  bf16x8 qf[12];
  {
    const ushort* qp = qb + ((size_t)(b * 2048 + qg) * 16 + h) * 192 + 8 * hi;
#pragma unroll
    for (int s = 0; s < 12; ++s) qf[s] = *(const bf16x8*)(qp + 16 * s);
  }

  f32x16 oacc[4];
#pragma unroll
  for (int db = 0; db < 4; ++db)
#pragma unroll
    for (int r = 0; r < 16; ++r) oacc[db][r] = 0.f;
  float m = -1e30f, l = 0.f;

  for (int kt = 0; kt < nkt; ++kt) {
    const int k0 = kt * 64;
    stage(k0);
    asm volatile("s_waitcnt vmcnt(0)" ::: "memory");
    __syncthreads();
    if (k0 <= q0w + 31) {
      // ---- QK^T: sub-blocks A (k0+kk) and B (k0+32+kk), independent chains ----
      f32x16 sA, sB;
#pragma unroll
      for (int r = 0; r < 16; ++r) { sA[r] = 0.f; sB[r] = 0.f; }
      __builtin_amdgcn_s_setprio(1);
#pragma unroll
      for (int s = 0; s < 12; ++s) {
        int ch = ((2 * s + hi) ^ kx) << 3;
        bf16x8 kfA = *(const bf16x8*)(Ks + lq * 200 + ch);
        bf16x8 kfB = *(const bf16x8*)(Ks + (lq + 32) * 200 + ch);
        sA = __builtin_amdgcn_mfma_f32_32x32x16_bf16(kfA, qf[s], sA, 0, 0, 0);
        sB = __builtin_amdgcn_mfma_f32_32x32x16_bf16(kfB, qf[s], sB, 0, 0, 0);
      }
      __builtin_amdgcn_s_setprio(0);
      float svA[16], svB[16];
#pragma unroll
      for (int r = 0; r < 16; ++r) { svA[r] = sA[r]; svB[r] = sB[r]; }
      if (k0 + 63 > q0w) {                   // diagonal region: causal mask
#pragma unroll
        for (int r = 0; r < 16; ++r) {
          int kk = (r & 3) + 8 * (r >> 2) + 4 * hi;
          if (k0 + kk > qg) svA[r] = -1e30f;
          if (k0 + 32 + kk > qg) svB[r] = -1e30f;
        }
      }
      // ---- online softmax over 32 values, defer-max (THR=8, exp2 domain) ----
      float pmax = fmaxf(svA[0], svB[0]);
#pragma unroll
      for (int r = 1; r < 16; ++r) pmax = fmaxf(pmax, fmaxf(svA[r], svB[r]));
      pmax = fmaxf(pmax, __shfl_xor(pmax, 32));
      float smax = pmax * SCALE2;
      if (!__all(smax - m <= 8.0f)) {
        float mnew = fmaxf(m, smax);
        float a = exp2f(m - mnew);
        l *= a;
#pragma unroll
        for (int db = 0; db < 4; ++db)
#pragma unroll
          for (int r = 0; r < 16; ++r) oacc[db][r] *= a;
        m = mnew;
      }
      float eA[16], eB[16]; float sum = 0.f;
#pragma unroll
      for (int r = 0; r < 16; ++r) {
        eA[r] = exp2f(svA[r] * SCALE2 - m);
        eB[r] = exp2f(svB[r] * SCALE2 - m);
        sum += eA[r] + eB[r];
      }
      sum += __shfl_xor(sum, 32);
      l += sum;
      // ---- P -> bf16 PV B-fragments (per sub-block, R7-verified pack) ----
      uint32_t pkA[8], pkB[8];
#pragma unroll
      for (int i = 0; i < 8; ++i) {
        pkA[i] = (uint32_t)f2bf(eA[2 * i]) | ((uint32_t)f2bf(eA[2 * i + 1]) << 16);
        pkB[i] = (uint32_t)f2bf(eB[2 * i]) | ((uint32_t)f2bf(eB[2 * i + 1]) << 16);
      }
      uint32_t swA[8], swB[8];
#pragma unroll
      for (int i = 0; i < 8; ++i) {
        swA[i] = (uint32_t)__shfl_xor((int)pkA[i], 32);
        swB[i] = (uint32_t)__shfl_xor((int)pkB[i], 32);
      }
      union { uint32_t u[4]; bf16x8 v; } pA0, pA1, pB0, pB1;
      pA0.u[0] = hi ? swA[2] : pkA[0];
      pA0.u[1] = hi ? swA[3] : pkA[1];
      pA0.u[2] = hi ? pkA[2] : swA[0];
      pA0.u[3] = hi ? pkA[3] : swA[1];
      pA1.u[0] = hi ? swA[6] : pkA[4];
      pA1.u[1] = hi ? swA[7] : pkA[5];
      pA1.u[2] = hi ? pkA[6] : swA[4];
      pA1.u[3] = hi ? pkA[7] : swA[5];
      pB0.u[0] = hi ? swB[2] : pkB[0];
      pB0.u[1] = hi ? swB[3] : pkB[1];
      pB0.u[2] = hi ? pkB[2] : swB[0];
      pB0.u[3] = hi ? pkB[3] : swB[1];
      pB1.u[0] = hi ? swB[6] : pkB[4];
      pB1.u[1] = hi ? swB[7] : pkB[5];
      pB1.u[2] = hi ? pkB[6] : swB[4];
      pB1.u[3] = hi ? pkB[7] : swB[5];
      // ---- PV: O^T[d][q] += V^T[d][k] P^T[k][q], k 0..63 in 4 slices ----
      __builtin_amdgcn_s_setprio(1);
#pragma unroll
      for (int db = 0; db < 4; ++db) {
        const int d = 32 * db + lq;
        const int vx = (d >> 3) & 7;
        const ushort* vr = Vs + d * 72;
        bf16x8 vf0 = *(const bf16x8*)(vr + (((0 + hi) ^ vx) << 3));
        bf16x8 vf1 = *(const bf16x8*)(vr + (((2 + hi) ^ vx) << 3));
        bf16x8 vf2 = *(const bf16x8*)(vr + (((4 + hi) ^ vx) << 3));
        bf16x8 vf3 = *(const bf16x8*)(vr + (((6 + hi) ^ vx) << 3));
        oacc[db] = __builtin_amdgcn_mfma_f32_32x32x16_bf16(vf0, pA0.v, oacc[db], 0, 0, 0);
        oacc[db] = __builtin_amdgcn_mfma_f32_32x32x16_bf16(vf1, pA1.v, oacc[db], 0, 0, 0);
        oacc[db] = __builtin_amdgcn_mfma_f32_32x32x16_bf16(vf2, pB0.v, oacc[db], 0, 0, 0);
        oacc[db] = __builtin_amdgcn_mfma_f32_32x32x16_bf16(vf3, pB1.v, oacc[db], 0, 0, 0);
      }
      __builtin_amdgcn_s_setprio(0);
    }
    asm volatile("s_waitcnt lgkmcnt(0)" ::: "memory");
    __syncthreads();
  }

  float inv = 1.f / l;
  ushort* op = aout + ((size_t)(b * 2048 + qg)) * 2048 + h * 128 + 4 * hi;
#pragma unroll
  for (int db = 0; db < 4; ++db)
#pragma unroll
    for (int i = 0; i < 8; ++i) {
      uint32_t u = (uint32_t)f2bf(oacc[db][2 * i] * inv) |
                   ((uint32_t)f2bf(oacc[db][2 * i + 1] * inv) << 16);
      int dbase = 32 * db + (i & 1) * 2 + (i >> 1) * 8;
      *(uint32_t*)(op + dbase) = u;
    }
}

// ---------------- launcher ----------------
extern "C" void kernel_launch(void* const* d_in, const int* in_sizes, int n_in,
                              void* d_out, int out_size, void* d_ws, size_t ws_size,
                              hipStream_t stream) {
  const float* x = (const float*)d_in[0];
  const float* fcos = (const float*)d_in[1];
  const float* fsin = (const float*)d_in[2];
  const float* wq_a = (const float*)d_in[3];
  const float* qnw = (const float*)d_in[4];
  const float* wq_b = (const float*)d_in[5];
  const float* wkv_a = (const float*)d_in[6];
  const float* kvnw = (const float*)d_in[7];
  const float* wkv_b = (const float*)d_in[8];
  const float* wo = (const float*)d_in[9];
  float* out = (float*)d_out;

  char* ws = (char*)d_ws;
  size_t off = 0;
  auto alloc = [&](size_t bytes) -> char* {
    char* p = ws + off;
    off += (bytes + 255) & ~(size_t)255;
    return p;
  };
  ushort* xb     = (ushort*)alloc(4096ull * 2048 * 2);
  ushort* wqkv_t = (ushort*)alloc(2176ull * 2048 * 2);   // rows 0-1535 wq_a^T, 1536-2111 wkv_a^T, rest pad
  ushort* wqb_t  = (ushort*)alloc(3072ull * 1536 * 2);
  ushort* wkvb_t = (ushort*)alloc(4096ull * 512 * 2);
  ushort* wo_t   = (ushort*)alloc(2048ull * 2048 * 2);
  float*  cqkv   = (float*)alloc(4096ull * 2112 * 4);    // fused q_lora | kv_lora | k_pe
  ushort* cqn    = (ushort*)alloc(4096ull * 1536 * 2);
  ushort* ckvn   = (ushort*)alloc(4096ull * 512 * 2);
  ushort* kbuf   = (ushort*)alloc(2ull * 16 * 2048 * 192 * 2);
  ushort* qbuf   = (ushort*)cqkv;   // reuse: cqkv dead after both norms
  ushort* aout   = xb;              // reuse: x dead after fused GEMM1
  ushort* vT     = wqkv_t;          // reuse: wqkv_t+wqb_t dead after GEMM2

  dim3 tb(32, 8);
  k_f32_to_bf16<<<2048, 256, 0, stream>>>(x, xb, 4096 * 2048 / 4);
  k_transpose_f32_bf16<<<dim3(48, 64), tb, 0, stream>>>(wq_a, wqkv_t, 2048, 1536);
  k_transpose_f32_bf16<<<dim3(18, 64), tb, 0, stream>>>(wkv_a, wqkv_t + 1536ull * 2048, 2048, 576);
  k_transpose_f32_bf16<<<dim3(96, 48), tb, 0, stream>>>(wq_b, wqb_t, 1536, 3072);
  k_transpose_f32_bf16<<<dim3(128, 16), tb, 0, stream>>>(wkv_b, wkvb_t, 512, 4096);
  k_transpose_f32_bf16<<<dim3(64, 64), tb, 0, stream>>>(wo, wo_t, 2048, 2048);

  // fused GEMM1: cqkv = xb @ [wq_a | wkv_a]  (M=4096, K=2048, Nreal=2112)
  k_gemm<float><<<dim3(17, 32), 256, 0, stream>>>(xb, wqkv_t, cqkv, 2048, 2112);

  k_rmsnorm_bf16<<<4096, 256, 0, stream>>>(cqkv, qnw, cqn, 1536, 2112);
  k_kvnorm_rope<<<4096, 256, 0, stream>>>(cqkv, kvnw, fcos, fsin, ckvn, kbuf);

  // q = cqn @ wq_b (K=1536, N=3072), bf16 out
  k_gemm<ushort><<<dim3(24, 32), 256, 0, stream>>>(cqn, wqb_t, qbuf, 1536, 3072);
  k_qrope<<<4096, 256, 0, stream>>>(qbuf, fcos, fsin);

  // kv = ckvn @ wkv_b (K=512, N=4096) -> kbuf + vT (scatter epilogue)
  k_gemm_kv<<<dim3(32, 32), 256, 0, stream>>>(ckvn, wkvb_t, kbuf, vT, 512);

  k_attn10<<<dim3(512), 256, 0, stream>>>(qbuf, kbuf, vT, aout);

  // out = aout @ wo (K=2048, N=2048), fp32 out
  k_gemm<float><<<dim3(16, 32), 256, 0, stream>>>(aout, wo_t, out, 2048, 2048);
}

// Round 15
// 354.752 us; speedup vs baseline: 1.1412x; 1.0939x over previous
//
#include <hip/hip_runtime.h>
#include <cstdint>
#include <cstddef>

// ---------------- common types / helpers ----------------
typedef __attribute__((ext_vector_type(8))) short bf16x8;
typedef __attribute__((ext_vector_type(4))) float f32x4;
typedef __attribute__((ext_vector_type(16))) float f32x16;

#define S_LEN 2048
#define SCALE2 0.10411754f   // 192^-0.5 * log2(e)

__device__ __forceinline__ ushort f2bf(float f) {
  uint32_t u = __float_as_uint(f);
  u = (u + 0x7FFFu + ((u >> 16) & 1u)) >> 16;
  return (ushort)u;
}
__device__ __forceinline__ float bf2f(ushort u) {
  return __uint_as_float(((uint32_t)u) << 16);
}

typedef __attribute__((address_space(1))) void GV;
typedef __attribute__((address_space(3))) void LV;
__device__ __forceinline__ void gload16(const void* g, void* l) {
  __builtin_amdgcn_global_load_lds((GV*)g, (LV*)l, 16, 0, 0);
}

__device__ __forceinline__ void store_out(float* p, float v) { *p = v; }
__device__ __forceinline__ void store_out(ushort* p, float v) { *p = f2bf(v); }

// ---------------- fp32 -> bf16 convert ----------------
__global__ void k_f32_to_bf16(const float* __restrict__ in, ushort* __restrict__ out, int n4) {
  int i = blockIdx.x * blockDim.x + threadIdx.x;
  int stride = gridDim.x * blockDim.x;
  for (; i < n4; i += stride) {
    float4 v = reinterpret_cast<const float4*>(in)[i];
    ushort4 o;
    o.x = f2bf(v.x); o.y = f2bf(v.y); o.z = f2bf(v.z); o.w = f2bf(v.w);
    reinterpret_cast<ushort4*>(out)[i] = o;
  }
}

// ---------------- fp32 (R,C) -> bf16 transposed (C,R) ----------------
__global__ void k_transpose_f32_bf16(const float* __restrict__ in, ushort* __restrict__ out,
                                     int R, int C) {
  __shared__ float tile[32][33];
  int c0 = blockIdx.x * 32, r0 = blockIdx.y * 32;
  int tx = threadIdx.x, ty = threadIdx.y;
#pragma unroll
  for (int i = 0; i < 32; i += 8) {
    int r = r0 + ty + i, c = c0 + tx;
    if (r < R && c < C) tile[ty + i][tx] = in[(size_t)r * C + c];
  }
  __syncthreads();
#pragma unroll
  for (int i = 0; i < 32; i += 8) {
    int c = c0 + ty + i, r = r0 + tx;
    if (r < R && c < C) out[(size_t)c * R + r] = f2bf(tile[tx][ty + i]);
  }
}

// ---------------- 128x128 BK=64 bf16 GEMM ----------------
// R15 delta vs the R1-R14-proven BK=32 form: K-step 64 (halves barrier/drain
// count; 32 MFMA per phase) + padded LDS rows (72 elems = 9 x 16B chunks, odd
// count -> row-step shifts banks by 4 -> 2-way-free ds_read_b128) with
// chunk-XOR swizzle cg = e ^ ((r>>3)&7) (involution; R14-V-staging-proven).
// Staging per matrix: 1152 slots, 18 wave-slots of 64, wave-uniform ii<18
// guard (R14 pattern). Explicit vmcnt(0) before barrier (R2/R4 lesson:
// __syncthreads does not reliably drain global_load_lds).
template <typename OUT>
__global__ __launch_bounds__(256) void k_gemm(const ushort* __restrict__ A,
                                              const ushort* __restrict__ Bt,
                                              OUT* __restrict__ C, int K, int Nreal) {
  __shared__ ushort As[128 * 72];   // 18432 B
  __shared__ ushort Bs[128 * 72];   // 18432 B
  const int t = threadIdx.x, lane = t & 63, w = t >> 6;
  const int nwg = gridDim.x * gridDim.y;
  const int wg = blockIdx.y * gridDim.x + blockIdx.x;
  const int swz = (wg & 7) * (nwg >> 3) + (wg >> 3);
  const int m0 = (swz / gridDim.x) * 128, n0 = (swz % gridDim.x) * 128;
  const int wm = (w >> 1) * 64, wn = (w & 1) * 64;
  const int g = lane >> 4, q = lane & 15;
  f32x4 acc[4][4] = {};
  for (int kt = 0; kt < K; kt += 64) {
    // ---- stage A and B tiles: 128 rows x 9 chunks each (slot e==8 = pad) ----
#pragma unroll
    for (int it = 0; it < 5; ++it) {
      int ii = it * 4 + w;
      if (ii < 18) {
        unsigned s = ii * 64 + lane;         // 0..1151
        int r = s / 9, e = s - r * 9;        // r<128, e<9
        int cg = e ^ ((r >> 3) & 7);
        if (cg > 7) cg = 0;                  // pad slot -> dummy load
        gload16(A + (size_t)(m0 + r) * K + kt + cg * 8, (char*)As + ii * 1024);
        gload16(Bt + (size_t)(n0 + r) * K + kt + cg * 8, (char*)Bs + ii * 1024);
      }
    }
    asm volatile("s_waitcnt vmcnt(0)" ::: "memory");
    __syncthreads();
#pragma unroll
    for (int kh = 0; kh < 2; ++kh) {
      bf16x8 af[4], bfr[4];
#pragma unroll
      for (int mi = 0; mi < 4; mi++) {
        int row = wm + 16 * mi + q;
        int rx = (row >> 3) & 7;
        af[mi] = *(const bf16x8*)(As + row * 72 + (((kh * 4 + g) ^ rx) << 3));
      }
#pragma unroll
      for (int ni = 0; ni < 4; ni++) {
        int row = wn + 16 * ni + q;
        int rx = (row >> 3) & 7;
        bfr[ni] = *(const bf16x8*)(Bs + row * 72 + (((kh * 4 + g) ^ rx) << 3));
      }
#pragma unroll
      for (int mi = 0; mi < 4; mi++)
#pragma unroll
        for (int ni = 0; ni < 4; ni++)
          acc[mi][ni] = __builtin_amdgcn_mfma_f32_16x16x32_bf16(af[mi], bfr[ni], acc[mi][ni], 0, 0, 0);
    }
    __syncthreads();
  }
#pragma unroll
  for (int mi = 0; mi < 4; mi++)
#pragma unroll
    for (int ni = 0; ni < 4; ni++) {
      int col = n0 + wn + 16 * ni + q;
      if (col < Nreal) {
        int row = m0 + wm + 16 * mi + 4 * g;
#pragma unroll
        for (int r = 0; r < 4; r++)
          store_out(&C[(size_t)(row + r) * Nreal + col], acc[mi][ni][r]);
      }
    }
}

// ---------------- kv GEMM (BK=64 variant): k_nope -> kbuf, V -> vT ----------------
__global__ __launch_bounds__(256) void k_gemm_kv(const ushort* __restrict__ A,
                                                 const ushort* __restrict__ Bt,
                                                 ushort* __restrict__ kbuf,
                                                 ushort* __restrict__ vT, int K) {
  __shared__ ushort As[128 * 72];
  __shared__ ushort Bs[128 * 72];
  const int t = threadIdx.x, lane = t & 63, w = t >> 6;
  const int nwg = gridDim.x * gridDim.y;
  const int wg = blockIdx.y * gridDim.x + blockIdx.x;
  const int swz = (wg & 7) * (nwg >> 3) + (wg >> 3);
  const int m0 = (swz / gridDim.x) * 128, n0 = (swz % gridDim.x) * 128;
  const int wm = (w >> 1) * 64, wn = (w & 1) * 64;
  const int g = lane >> 4, q = lane & 15;
  f32x4 acc[4][4] = {};
  for (int kt = 0; kt < K; kt += 64) {
#pragma unroll
    for (int it = 0; it < 5; ++it) {
      int ii = it * 4 + w;
      if (ii < 18) {
        unsigned s = ii * 64 + lane;
        int r = s / 9, e = s - r * 9;
        int cg = e ^ ((r >> 3) & 7);
        if (cg > 7) cg = 0;
        gload16(A + (size_t)(m0 + r) * K + kt + cg * 8, (char*)As + ii * 1024);
        gload16(Bt + (size_t)(n0 + r) * K + kt + cg * 8, (char*)Bs + ii * 1024);
      }
    }
    asm volatile("s_waitcnt vmcnt(0)" ::: "memory");
    __syncthreads();
#pragma unroll
    for (int kh = 0; kh < 2; ++kh) {
      bf16x8 af[4], bfr[4];
#pragma unroll
      for (int mi = 0; mi < 4; mi++) {
        int row = wm + 16 * mi + q;
        int rx = (row >> 3) & 7;
        af[mi] = *(const bf16x8*)(As + row * 72 + (((kh * 4 + g) ^ rx) << 3));
      }
#pragma unroll
      for (int ni = 0; ni < 4; ni++) {
        int row = wn + 16 * ni + q;
        int rx = (row >> 3) & 7;
        bfr[ni] = *(const bf16x8*)(Bs + row * 72 + (((kh * 4 + g) ^ rx) << 3));
      }
#pragma unroll
      for (int mi = 0; mi < 4; mi++)
#pragma unroll
        for (int ni = 0; ni < 4; ni++)
          acc[mi][ni] = __builtin_amdgcn_mfma_f32_16x16x32_bf16(af[mi], bfr[ni], acc[mi][ni], 0, 0, 0);
    }
    __syncthreads();
  }
#pragma unroll
  for (int mi = 0; mi < 4; mi++)
#pragma unroll
    for (int ni = 0; ni < 4; ni++) {
      int col = n0 + wn + 16 * ni + q;     // 0..4095
      int hh = col >> 8, jj = col & 255;
      int row0 = m0 + wm + 16 * mi + 4 * g;
#pragma unroll
      for (int r = 0; r < 4; r++) {
        int tok = row0 + r;
        int bb = tok >> 11, ss = tok & 2047;
        ushort v = f2bf(acc[mi][ni][r]);
        if (jj < 128)
          kbuf[((size_t)(bb * 16 + hh) * 2048 + ss) * 192 + jj] = v;
        else
          vT[((size_t)(bb * 16 + hh) * 128 + (jj - 128)) * 2048 + ss] = v;
      }
    }
}

// ---------------- RMSNorm (fp32 in strided rows, bf16 out) ----------------
__global__ void k_rmsnorm_bf16(const float* __restrict__ in, const float* __restrict__ w,
                               ushort* __restrict__ out, int D, int instride) {
  int row = blockIdx.x;
  const float* x = in + (size_t)row * instride;
  ushort* o = out + (size_t)row * D;
  float ss = 0.f;
  for (int i = threadIdx.x; i < D; i += 256) { float v = x[i]; ss += v * v; }
#pragma unroll
  for (int m = 1; m < 64; m <<= 1) ss += __shfl_xor(ss, m);
  __shared__ float red[4];
  if ((threadIdx.x & 63) == 0) red[threadIdx.x >> 6] = ss;
  __syncthreads();
  float tot = red[0] + red[1] + red[2] + red[3];
  float sc = rsqrtf(tot / (float)D + 1e-6f);
  for (int i = threadIdx.x; i < D; i += 256) o[i] = f2bf(x[i] * sc * w[i]);
}

// ---------------- kv RMSNorm (512) + k_pe rope broadcast into kbuf ----------------
__global__ void k_kvnorm_rope(const float* __restrict__ cqkv, const float* __restrict__ w,
                              const float* __restrict__ cosT, const float* __restrict__ sinT,
                              ushort* __restrict__ ckvn, ushort* __restrict__ kbuf) {
  int tok = blockIdx.x, b = tok >> 11, s = tok & 2047;
  const float* x = cqkv + (size_t)tok * 2112 + 1536;
  float ss = 0.f;
  for (int i = threadIdx.x; i < 512; i += 256) { float v = x[i]; ss += v * v; }
#pragma unroll
  for (int m = 1; m < 64; m <<= 1) ss += __shfl_xor(ss, m);
  __shared__ float red[4];
  if ((threadIdx.x & 63) == 0) red[threadIdx.x >> 6] = ss;
  __syncthreads();
  float tot = red[0] + red[1] + red[2] + red[3];
  float sc = rsqrtf(tot / 512.f + 1e-6f);
  for (int i = threadIdx.x; i < 512; i += 256) ckvn[(size_t)tok * 512 + i] = f2bf(x[i] * sc * w[i]);
  if (threadIdx.x < 32) {
    int i = threadIdx.x;
    float xr = x[512 + 2 * i], xi = x[512 + 2 * i + 1];
    float c = cosT[s * 32 + i], sn = sinT[s * 32 + i];
    uint32_t lo = f2bf(xr * c - xi * sn);
    uint32_t hi = f2bf(xr * sn + xi * c);
    uint32_t pk = lo | (hi << 16);
#pragma unroll
    for (int h = 0; h < 16; ++h)
      *(uint32_t*)(kbuf + ((size_t)(b * 16 + h) * 2048 + s) * 192 + 128 + 2 * i) = pk;
  }
}

// ---------------- q rope, in-place on bf16 q (4096, 16, 192) ----------------
__global__ void k_qrope(ushort* __restrict__ qb, const float* __restrict__ cosT,
                        const float* __restrict__ sinT) {
  int tok = blockIdx.x, s = tok & (S_LEN - 1);
  for (int pp = threadIdx.x; pp < 512; pp += 256) {
    int h = pp >> 5, i = pp & 31;
    ushort* base = qb + ((size_t)tok * 16 + h) * 192 + 128;
    float xr = bf2f(base[2 * i]), xi = bf2f(base[2 * i + 1]);
    float c = cosT[s * 32 + i], sn = sinT[s * 32 + i];
    base[2 * i] = f2bf(xr * c - xi * sn);
    base[2 * i + 1] = f2bf(xr * sn + xi * c);
  }
}

// ---------------- causal flash attention (R14-proven: 112.4 us) ----------------
__global__ __launch_bounds__(256, 2) void k_attn10(const ushort* __restrict__ qb,
                                                   const ushort* __restrict__ kb,
                                                   const ushort* __restrict__ vT,
                                                   ushort* __restrict__ aout) {
  const int id = blockIdx.x;
  const int qt = 15 - (id >> 5);             // heavy-first (R7-proven mapping)
  const int bh = id & 31;
  const int h = bh & 15, b = bh >> 4;

  const int t = threadIdx.x, lane = t & 63, w = t >> 6;
  const int lq = lane & 31, hi = lane >> 5;
  const int kx = (lq >> 3) & 3;

  __shared__ ushort Ks[64 * 200];   // 25600 B
  __shared__ ushort Vs[128 * 72];   // 18432 B

  const ushort* kh = kb + (size_t)(b * 16 + h) * (2048 * 192);
  const ushort* vh = vT + (size_t)(b * 16 + h) * (128 * 2048);

  auto stage = [&](int k0) {
#pragma unroll
    for (int it = 0; it < 7; ++it) {
      int ii = it * 4 + w;
      if (ii < 25) {
        unsigned s = ii * 64 + lane;         // 0..1599
        int r = s / 25, e = s - r * 25;      // r<64, e<25 (e==24 pad)
        int cg = e ^ ((r >> 3) & 3);
        if (cg > 23) cg = 0;
        gload16(kh + (size_t)(k0 + r) * 192 + cg * 8, (char*)Ks + ii * 1024);
      }
    }
#pragma unroll
    for (int it = 0; it < 5; ++it) {
      int ii = it * 4 + w;
      if (ii < 18) {
        unsigned s = ii * 64 + lane;         // 0..1151
        int r = s / 9, e = s - r * 9;        // r<128, e<9 (e==8 pad)
        int cg = e ^ ((r >> 3) & 7);
        if (cg > 7) cg = 0;
        gload16(vh + (size_t)r * 2048 + k0 + cg * 8, (char*)Vs + ii * 1024);
      }
    }
  };

  const int q0 = qt * 128;
  const int q0w = q0 + 32 * w;
  const int qg = q0w + lq;
  const int nkt = qt * 2 + 2;

  bf16x8 qf[12];
  {
    const ushort* qp = qb + ((size_t)(b * 2048 + qg) * 16 + h) * 192 + 8 * hi;
#pragma unroll
    for (int s = 0; s < 12; ++s) qf[s] = *(const bf16x8*)(qp + 16 * s);
  }

  f32x16 oacc[4];
#pragma unroll
  for (int db = 0; db < 4; ++db)
#pragma unroll
    for (int r = 0; r < 16; ++r) oacc[db][r] = 0.f;
  float m = -1e30f, l = 0.f;

  for (int kt = 0; kt < nkt; ++kt) {
    const int k0 = kt * 64;
    stage(k0);
    asm volatile("s_waitcnt vmcnt(0)" ::: "memory");
    __syncthreads();
    if (k0 <= q0w + 31) {
      f32x16 sA, sB;
#pragma unroll
      for (int r = 0; r < 16; ++r) { sA[r] = 0.f; sB[r] = 0.f; }
      __builtin_amdgcn_s_setprio(1);
#pragma unroll
      for (int s = 0; s < 12; ++s) {
        int ch = ((2 * s + hi) ^ kx) << 3;
        bf16x8 kfA = *(const bf16x8*)(Ks + lq * 200 + ch);
        bf16x8 kfB = *(const bf16x8*)(Ks + (lq + 32) * 200 + ch);
        sA = __builtin_amdgcn_mfma_f32_32x32x16_bf16(kfA, qf[s], sA, 0, 0, 0);
        sB = __builtin_amdgcn_mfma_f32_32x32x16_bf16(kfB, qf[s], sB, 0, 0, 0);
      }
      __builtin_amdgcn_s_setprio(0);
      float svA[16], svB[16];
#pragma unroll
      for (int r = 0; r < 16; ++r) { svA[r] = sA[r]; svB[r] = sB[r]; }
      if (k0 + 63 > q0w) {
#pragma unroll
        for (int r = 0; r < 16; ++r) {
          int kk = (r & 3) + 8 * (r >> 2) + 4 * hi;
          if (k0 + kk > qg) svA[r] = -1e30f;
          if (k0 + 32 + kk > qg) svB[r] = -1e30f;
        }
      }
      float pmax = fmaxf(svA[0], svB[0]);
#pragma unroll
      for (int r = 1; r < 16; ++r) pmax = fmaxf(pmax, fmaxf(svA[r], svB[r]));
      pmax = fmaxf(pmax, __shfl_xor(pmax, 32));
      float smax = pmax * SCALE2;
      if (!__all(smax - m <= 8.0f)) {
        float mnew = fmaxf(m, smax);
        float a = exp2f(m - mnew);
        l *= a;
#pragma unroll
        for (int db = 0; db < 4; ++db)
#pragma unroll
          for (int r = 0; r < 16; ++r) oacc[db][r] *= a;
        m = mnew;
      }
      float eA[16], eB[16]; float sum = 0.f;
#pragma unroll
      for (int r = 0; r < 16; ++r) {
        eA[r] = exp2f(svA[r] * SCALE2 - m);
        eB[r] = exp2f(svB[r] * SCALE2 - m);
        sum += eA[r] + eB[r];
      }
      sum += __shfl_xor(sum, 32);
      l += sum;
      uint32_t pkA[8], pkB[8];
#pragma unroll
      for (int i = 0; i < 8; ++i) {
        pkA[i] = (uint32_t)f2bf(eA[2 * i]) | ((uint32_t)f2bf(eA[2 * i + 1]) << 16);
        pkB[i] = (uint32_t)f2bf(eB[2 * i]) | ((uint32_t)f2bf(eB[2 * i + 1]) << 16);
      }
      uint32_t swA[8], swB[8];
#pragma unroll
      for (int i = 0; i < 8; ++i) {
        swA[i] = (uint32_t)__shfl_xor((int)pkA[i], 32);
        swB[i] = (uint32_t)__shfl_xor((int)pkB[i], 32);
      }
      union { uint32_t u[4]; bf16x8 v; } pA0, pA1, pB0, pB1;
      pA0.u[0] = hi ? swA[2] : pkA[0];
      pA0.u[1] = hi ? swA[3] : pkA[1];
      pA0.u[2] = hi ? pkA[2] : swA[0];
      pA0.u[3] = hi ? pkA[3] : swA[1];
      pA1.u[0] = hi ? swA[6] : pkA[4];
      pA1.u[1] = hi ? swA[7] : pkA[5];
      pA1.u[2] = hi ? pkA[6] : swA[4];
      pA1.u[3] = hi ? pkA[7] : swA[5];
      pB0.u[0] = hi ? swB[2] : pkB[0];
      pB0.u[1] = hi ? swB[3] : pkB[1];
      pB0.u[2] = hi ? pkB[2] : swB[0];
      pB0.u[3] = hi ? pkB[3] : swB[1];
      pB1.u[0] = hi ? swB[6] : pkB[4];
      pB1.u[1] = hi ? swB[7] : pkB[5];
      pB1.u[2] = hi ? pkB[6] : swB[4];
      pB1.u[3] = hi ? pkB[7] : swB[5];
      __builtin_amdgcn_s_setprio(1);
#pragma unroll
      for (int db = 0; db < 4; ++db) {
        const int d = 32 * db + lq;
        const int vx = (d >> 3) & 7;
        const ushort* vr = Vs + d * 72;
        bf16x8 vf0 = *(const bf16x8*)(vr + (((0 + hi) ^ vx) << 3));
        bf16x8 vf1 = *(const bf16x8*)(vr + (((2 + hi) ^ vx) << 3));
        bf16x8 vf2 = *(const bf16x8*)(vr + (((4 + hi) ^ vx) << 3));
        bf16x8 vf3 = *(const bf16x8*)(vr + (((6 + hi) ^ vx) << 3));
        oacc[db] = __builtin_amdgcn_mfma_f32_32x32x16_bf16(vf0, pA0.v, oacc[db], 0, 0, 0);
        oacc[db] = __builtin_amdgcn_mfma_f32_32x32x16_bf16(vf1, pA1.v, oacc[db], 0, 0, 0);
        oacc[db] = __builtin_amdgcn_mfma_f32_32x32x16_bf16(vf2, pB0.v, oacc[db], 0, 0, 0);
        oacc[db] = __builtin_amdgcn_mfma_f32_32x32x16_bf16(vf3, pB1.v, oacc[db], 0, 0, 0);
      }
      __builtin_amdgcn_s_setprio(0);
    }
    asm volatile("s_waitcnt lgkmcnt(0)" ::: "memory");
    __syncthreads();
  }

  float inv = 1.f / l;
  ushort* op = aout + ((size_t)(b * 2048 + qg)) * 2048 + h * 128 + 4 * hi;
#pragma unroll
  for (int db = 0; db < 4; ++db)
#pragma unroll
    for (int i = 0; i < 8; ++i) {
      uint32_t u = (uint32_t)f2bf(oacc[db][2 * i] * inv) |
                   ((uint32_t)f2bf(oacc[db][2 * i + 1] * inv) << 16);
      int dbase = 32 * db + (i & 1) * 2 + (i >> 1) * 8;
      *(uint32_t*)(op + dbase) = u;
    }
}

// ---------------- launcher ----------------
extern "C" void kernel_launch(void* const* d_in, const int* in_sizes, int n_in,
                              void* d_out, int out_size, void* d_ws, size_t ws_size,
                              hipStream_t stream) {
  const float* x = (const float*)d_in[0];
  const float* fcos = (const float*)d_in[1];
  const float* fsin = (const float*)d_in[2];
  const float* wq_a = (const float*)d_in[3];
  const float* qnw = (const float*)d_in[4];
  const float* wq_b = (const float*)d_in[5];
  const float* wkv_a = (const float*)d_in[6];
  const float* kvnw = (const float*)d_in[7];
  const float* wkv_b = (const float*)d_in[8];
  const float* wo = (const float*)d_in[9];
  float* out = (float*)d_out;

  char* ws = (char*)d_ws;
  size_t off = 0;
  auto alloc = [&](size_t bytes) -> char* {
    char* p = ws + off;
    off += (bytes + 255) & ~(size_t)255;
    return p;
  };
  ushort* xb     = (ushort*)alloc(4096ull * 2048 * 2);
  ushort* wqkv_t = (ushort*)alloc(2176ull * 2048 * 2);   // rows 0-1535 wq_a^T, 1536-2111 wkv_a^T, rest pad
  ushort* wqb_t  = (ushort*)alloc(3072ull * 1536 * 2);
  ushort* wkvb_t = (ushort*)alloc(4096ull * 512 * 2);
  ushort* wo_t   = (ushort*)alloc(2048ull * 2048 * 2);
  float*  cqkv   = (float*)alloc(4096ull * 2112 * 4);    // fused q_lora | kv_lora | k_pe
  ushort* cqn    = (ushort*)alloc(4096ull * 1536 * 2);
  ushort* ckvn   = (ushort*)alloc(4096ull * 512 * 2);
  ushort* kbuf   = (ushort*)alloc(2ull * 16 * 2048 * 192 * 2);
  ushort* qbuf   = (ushort*)cqkv;   // reuse: cqkv dead after both norms
  ushort* aout   = xb;              // reuse: x dead after fused GEMM1
  ushort* vT     = wqkv_t;          // reuse: wqkv_t+wqb_t dead after GEMM2

  dim3 tb(32, 8);
  k_f32_to_bf16<<<2048, 256, 0, stream>>>(x, xb, 4096 * 2048 / 4);
  k_transpose_f32_bf16<<<dim3(48, 64), tb, 0, stream>>>(wq_a, wqkv_t, 2048, 1536);
  k_transpose_f32_bf16<<<dim3(18, 64), tb, 0, stream>>>(wkv_a, wqkv_t + 1536ull * 2048, 2048, 576);
  k_transpose_f32_bf16<<<dim3(96, 48), tb, 0, stream>>>(wq_b, wqb_t, 1536, 3072);
  k_transpose_f32_bf16<<<dim3(128, 16), tb, 0, stream>>>(wkv_b, wkvb_t, 512, 4096);
  k_transpose_f32_bf16<<<dim3(64, 64), tb, 0, stream>>>(wo, wo_t, 2048, 2048);

  // fused GEMM1: cqkv = xb @ [wq_a | wkv_a]  (M=4096, K=2048, Nreal=2112)
  k_gemm<float><<<dim3(17, 32), 256, 0, stream>>>(xb, wqkv_t, cqkv, 2048, 2112);

  k_rmsnorm_bf16<<<4096, 256, 0, stream>>>(cqkv, qnw, cqn, 1536, 2112);
  k_kvnorm_rope<<<4096, 256, 0, stream>>>(cqkv, kvnw, fcos, fsin, ckvn, kbuf);

  // q = cqn @ wq_b (K=1536, N=3072), bf16 out
  k_gemm<ushort><<<dim3(24, 32), 256, 0, stream>>>(cqn, wqb_t, qbuf, 1536, 3072);
  k_qrope<<<4096, 256, 0, stream>>>(qbuf, fcos, fsin);

  // kv = ckvn @ wkv_b (K=512, N=4096) -> kbuf + vT (scatter epilogue)
  k_gemm_kv<<<dim3(32, 32), 256, 0, stream>>>(ckvn, wkvb_t, kbuf, vT, 512);

  k_attn10<<<dim3(512), 256, 0, stream>>>(qbuf, kbuf, vT, aout);

  // out = aout @ wo (K=2048, N=2048), fp32 out
  k_gemm<float><<<dim3(16, 32), 256, 0, stream>>>(aout, wo_t, out, 2048, 2048);
}